// Round 2
// baseline (337.005 us; speedup 1.0000x reference)
//
#include <hip/hip_runtime.h>

// CML1D: 15-step coupled map lattice, fp32, rows=2048, L=16384.
//   m = R*g*(1-g)
//   g' = c0*m[i-1] + c1*m[i] + c2*m[i+1] + BETA*d   (circular)
//   c0=(1-B)E*K0, c1=(1-B)(1-E)+(1-B)E*K1, c2=(1-B)E*K2
// out = clip(g, 1e-4, 1-1e-4) after 15 steps.
//
// R2: barrier-free ghost-zone decomposition. Each WAVE independently owns
// 1088 contiguous cells (64 lanes x 17 regs), stores the middle 1024.
// 32-cell ghost per side > 15 steps of edge-garbage propagation, so waves
// never synchronize. Per-step halo = 2 intra-wave __shfl (ds_bpermute, no
// barrier). Lane 0 / lane 63 shfl edge values are garbage by design -- they
// only pollute ghost cells. Zero __syncthreads in the kernel.

constexpr float Rc    = 3.9f;
constexpr float EPSc  = 0.3f;
constexpr float BETAc = 0.15f;
constexpr int   STEPS = 15;
constexpr int   L     = 16384;   // power of two -> circular wrap via & (L-1)
constexpr int   CE    = 17;      // extended cells per lane
constexpr int   SEG   = 1024;    // valid output cells per wave
constexpr int   GHOST = 32;      // ghost cells per side (>= STEPS+1)
constexpr int   TPB   = 256;     // 4 independent waves per block
constexpr int   SEGS_PER_ROW = L / SEG;  // 16

__global__ __launch_bounds__(TPB)
void cml1d_kernel(const float* __restrict__ drive,
                  const float* __restrict__ K,
                  float* __restrict__ out) {
    const int lane  = threadIdx.x & 63;
    const int wave  = threadIdx.x >> 6;
    const int gwave = blockIdx.x * (TPB / 64) + wave;
    const int row   = gwave >> 4;          // /SEGS_PER_ROW
    const int seg   = gwave & (SEGS_PER_ROW - 1);
    const size_t rowbase = (size_t)row * L;
    const int cstart = seg * SEG - GHOST + lane * CE;  // may be negative: wrap

    const float K0 = K[0], K1 = K[1], K2 = K[2];
    const float A  = (1.0f - BETAc) * (1.0f - EPSc);
    const float B  = (1.0f - BETAc) * EPSc;
    const float c0 = B * K0;
    const float c1 = A + B * K1;
    const float c2 = B * K2;

    float g[CE], bd[CE];
    #pragma unroll
    for (int i = 0; i < CE; ++i) {
        int idx = (cstart + i) & (L - 1);   // circular (handles negative too,
                                            // since cstart >= -32 and &16383
                                            // of the 2's-comp value wraps)
        float v = drive[rowbase + (size_t)idx];
        g[i]  = v;
        bd[i] = BETAc * v;
    }

    for (int s = 0; s < STEPS; ++s) {
        // endpoint logistic maps, published to neighbor lanes (no barrier)
        float t0    = Rc * g[0];
        float m0    = t0 - t0 * g[0];
        float t1    = Rc * g[CE - 1];
        float mlast = t1 - t1 * g[CE - 1];
        float mleft  = __shfl_up(mlast, 1);   // lane 0: garbage -> ghost only
        float mright = __shfl_down(m0, 1);    // lane 63: garbage -> ghost only

        float mprev = mleft;
        float mcur  = m0;
        #pragma unroll
        for (int i = 0; i < CE; ++i) {
            float mnext;
            if (i == CE - 1)      mnext = mright;
            else if (i == CE - 2) mnext = mlast;
            else {
                float tt = Rc * g[i + 1];
                mnext = tt - tt * g[i + 1];
            }
            g[i] = fmaf(c0, mprev, fmaf(c1, mcur, fmaf(c2, mnext, bd[i])));
            mprev = mcur;
            mcur  = mnext;
        }
    }

    const float lo = 0.0001f;
    const float hi = 0.9999f;   // float(1.0 - 0.0001)
    #pragma unroll
    for (int i = 0; i < CE; ++i) {
        int pos = lane * CE + i;            // position in extended segment
        if (pos >= GHOST && pos < GHOST + SEG) {
            int idx = (cstart + i) & (L - 1);
            out[rowbase + (size_t)idx] = fminf(fmaxf(g[i], lo), hi);
        }
    }
}

extern "C" void kernel_launch(void* const* d_in, const int* in_sizes, int n_in,
                              void* d_out, int out_size, void* d_ws, size_t ws_size,
                              hipStream_t stream) {
    const float* drive = (const float*)d_in[0];
    const float* K     = (const float*)d_in[1];
    float* out         = (float*)d_out;
    const int rows   = in_sizes[0] / L;               // 2048
    const int gwaves = rows * SEGS_PER_ROW;           // 32768
    const int blocks = gwaves / (TPB / 64);           // 8192
    cml1d_kernel<<<dim3(blocks), dim3(TPB), 0, stream>>>(drive, K, out);
}

// Round 3
// 234.257 us; speedup vs baseline: 1.4386x; 1.4386x over previous
//
#include <hip/hip_runtime.h>

// CML1D: 15-step coupled map lattice, fp32, rows=2048, L=16384.
//   m = R*g*(1-g);  g' = c0*m[i-1] + c1*m[i] + c2*m[i+1] + BETA*d (circular)
//   c0=(1-B)E*K0, c1=(1-B)(1-E)+(1-B)E*K1, c2=(1-B)E*K2
// out = clip(g, 1e-4, 1-1e-4) after 15 steps.
//
// R3: barrier-free wave ghost zones (R2) + LDS-staged coalesced I/O.
//   - Each wave owns 1088 contiguous cells (64 lanes x 17), stores middle 1024.
//     GHOST=32 > 15 steps of edge-garbage propagation -> waves never sync.
//   - I/O goes through a private per-wave LDS slot: global float4 (coalesced)
//     <-> LDS <-> stride-17 register chunks. Stride 17 odd -> 2-way bank
//     aliasing only (free). DS ops are in-order within a wave, so no
//     __syncthreads anywhere; wave_barrier() only blocks compiler reordering.
//   - Hot loop is register-only: 2 shuffles + 17*(2+3) VALU per step.

constexpr float Rc    = 3.9f;
constexpr float EPSc  = 0.3f;
constexpr float BETAc = 0.15f;
constexpr int   STEPS = 15;
constexpr int   L     = 16384;
constexpr int   CE    = 17;           // cells per lane (extended)
constexpr int   SEG   = 1024;         // valid cells per wave
constexpr int   GHOST = 32;           // ghost cells per side
constexpr int   EXT   = SEG + 2*GHOST;  // 1088
constexpr int   TPB   = 256;
constexpr int   WPB   = TPB / 64;     // 4 waves per block

__global__ __launch_bounds__(TPB)
void cml1d_kernel(const float* __restrict__ drive,
                  const float* __restrict__ K,
                  float* __restrict__ out) {
    __shared__ float lds[WPB][EXT];   // 4*1088*4 = 17408 B, per-wave private slots

    const int lane = threadIdx.x & 63;
    const int wv   = threadIdx.x >> 6;
    const int gw   = blockIdx.x * WPB + wv;
    const int row  = gw >> 4;                 // 16 segments per row
    const int seg  = gw & 15;
    const size_t rowbase = (size_t)row * L;
    const int wbase = seg * SEG - GHOST;      // extended window start (may be <0)

    // ---- coalesced load: 272 float4 per wave (rounds of 64 lanes) -> LDS ----
    #pragma unroll
    for (int j = 0; j < 5; ++j) {
        int f = j * 64 + lane;
        if (f < EXT / 4) {
            int e   = wbase + f * 4;          // multiple of 4; window wrap is
            int idx = e & (L - 1);            // also multiple of 4 -> float4 safe
            float4 v = *reinterpret_cast<const float4*>(drive + rowbase + idx);
            *reinterpret_cast<float4*>(&lds[wv][f * 4]) = v;
        }
    }
    __builtin_amdgcn_wave_barrier();  // keep ds_write before ds_read in program order

    const float K0 = K[0], K1 = K[1], K2 = K[2];
    const float A  = (1.0f - BETAc) * (1.0f - EPSc);
    const float B  = (1.0f - BETAc) * EPSc;
    const float c0 = B * K0;
    const float c1 = A + B * K1;
    const float c2 = B * K2;

    // ---- LDS -> registers: lane's 17 contiguous cells (stride 17: 2-way, free)
    float g[CE], bd[CE];
    #pragma unroll
    for (int i = 0; i < CE; ++i) {
        float v = lds[wv][lane * CE + i];
        g[i]  = v;
        bd[i] = BETAc * v;
    }

    // ---- 15 steps, register-only, no barriers ----
    for (int s = 0; s < STEPS; ++s) {
        float t0    = Rc * g[0];
        float m0    = fmaf(-t0, g[0], t0);        // R*g*(1-g)
        float t1    = Rc * g[CE - 1];
        float mlast = fmaf(-t1, g[CE - 1], t1);
        float mleft  = __shfl_up(mlast, 1);       // lane 0: garbage -> ghost only
        float mright = __shfl_down(m0, 1);        // lane 63: garbage -> ghost only

        float mprev = mleft;
        float mcur  = m0;
        #pragma unroll
        for (int i = 0; i < CE; ++i) {
            float mnext;
            if (i == CE - 1)      mnext = mright;
            else if (i == CE - 2) mnext = mlast;
            else {
                float tt = Rc * g[i + 1];
                mnext = fmaf(-tt, g[i + 1], tt);
            }
            g[i] = fmaf(c0, mprev, fmaf(c1, mcur, fmaf(c2, mnext, bd[i])));
            mprev = mcur;
            mcur  = mnext;
        }
    }

    // ---- registers -> LDS -> coalesced float4 stores of valid middle 1024 ----
    __builtin_amdgcn_wave_barrier();
    #pragma unroll
    for (int i = 0; i < CE; ++i) lds[wv][lane * CE + i] = g[i];
    __builtin_amdgcn_wave_barrier();

    const float lo = 0.0001f;
    const float hi = 0.9999f;   // float(1.0 - 0.0001)
    #pragma unroll
    for (int j = 0; j < 4; ++j) {
        int f = j * 64 + lane;                    // 256 float4 = 1024 floats
        float4 v = *reinterpret_cast<float4*>(&lds[wv][GHOST + f * 4]);
        v.x = fminf(fmaxf(v.x, lo), hi);
        v.y = fminf(fmaxf(v.y, lo), hi);
        v.z = fminf(fmaxf(v.z, lo), hi);
        v.w = fminf(fmaxf(v.w, lo), hi);
        *reinterpret_cast<float4*>(out + rowbase + seg * SEG + f * 4) = v;
    }
}

extern "C" void kernel_launch(void* const* d_in, const int* in_sizes, int n_in,
                              void* d_out, int out_size, void* d_ws, size_t ws_size,
                              hipStream_t stream) {
    const float* drive = (const float*)d_in[0];
    const float* K     = (const float*)d_in[1];
    float* out         = (float*)d_out;
    const int rows   = in_sizes[0] / L;           // 2048
    const int gwaves = rows * (L / SEG);          // 32768
    const int blocks = gwaves / WPB;              // 8192
    cml1d_kernel<<<dim3(blocks), dim3(TPB), 0, stream>>>(drive, K, out);
}